// Round 9
// baseline (372.061 us; speedup 1.0000x reference)
//
#include <hip/hip_runtime.h>
#include <hip/hip_bf16.h>

typedef __bf16 bf16x8 __attribute__((ext_vector_type(8)));
typedef __bf16 bf16x4 __attribute__((ext_vector_type(4)));
typedef float  f32x4  __attribute__((ext_vector_type(4)));

#define HID   256
#define BM    64
#define PITCH 264

// gate order: 0=ir 1=iz 2=in 3=hz 4=hn
__global__ void __launch_bounds__(256) prepack_frag(
    const float* __restrict__ w0, const float* __restrict__ w1,
    const float* __restrict__ w2, const float* __restrict__ w3,
    const float* __restrict__ w4, __bf16* __restrict__ wb)
{
    int t    = blockIdx.x * 256 + threadIdx.x;   // 40960 total
    int lane = t & 63;
    int cb   = (t >> 6) & 15;
    int gk   = t >> 10;
    int g    = gk % 5;
    int ks   = gk / 5;
    const float* W = g == 0 ? w0 : g == 1 ? w1 : g == 2 ? w2 : g == 3 ? w3 : w4;
    int row = cb * 16 + (lane & 15);
    int k0  = ks * 32 + (lane >> 4) * 8;
    float4 p = *(const float4*)(W + row * HID + k0);
    float4 q = *(const float4*)(W + row * HID + k0 + 4);
    bf16x8 o;
    o[0]=(__bf16)p.x; o[1]=(__bf16)p.y; o[2]=(__bf16)p.z; o[3]=(__bf16)p.w;
    o[4]=(__bf16)q.x; o[5]=(__bf16)q.y; o[6]=(__bf16)q.z; o[7]=(__bf16)q.w;
    *(bf16x8*)(wb + (size_t)t * 8) = o;
}

#define MFMA1(D, A_, B_) D = __builtin_amdgcn_mfma_f32_16x16x32_bf16(A_, B_, D, 0, 0, 0)

#define MFMA12(MF, AX, AH, B_) do {                                   \
    _Pragma("unroll")                                                 \
    for (int nf = 0; nf < 2; ++nf) {                                  \
        MFMA1(az[MF][nf],  AX, B_[2 + nf]);                           \
        MFMA1(ar[MF][nf],  AX, B_[0 + nf]);                           \
        MFMA1(anx[MF][nf], AX, B_[4 + nf]);                           \
        MFMA1(az[MF][nf],  AH, B_[6 + nf]);                           \
        MFMA1(ar[MF][nf],  AH, B_[6 + nf]);                           \
        MFMA1(anh[MF][nf], AH, B_[8 + nf]);                           \
    }                                                                 \
} while (0)

#define LOADB(DST, KK) do {                                           \
    _Pragma("unroll")                                                 \
    for (int g = 0; g < 5; ++g)                                       \
        _Pragma("unroll")                                             \
        for (int nf = 0; nf < 2; ++nf)                                \
            DST[g * 2 + nf] =                                         \
                *(const bf16x8*)(wbase + ((KK) * 5 + g) * 8192 + nf * 512); \
} while (0)

#define LOADB_SLOW(DST, KK) do {                                      \
    _Pragma("unroll")                                                 \
    for (int g = 0; g < 5; ++g)                                       \
        _Pragma("unroll")                                             \
        for (int nf = 0; nf < 2; ++nf) {                              \
            const float* pp = wsrc[g] + ((wn * 2 + nf) * 16 + lr) * HID + (KK) * 32 + lg * 8; \
            float4 c0 = *(const float4*)(pp), c1 = *(const float4*)(pp + 4); \
            bf16x8 u;                                                 \
            u[0]=(__bf16)c0.x; u[1]=(__bf16)c0.y; u[2]=(__bf16)c0.z; u[3]=(__bf16)c0.w; \
            u[4]=(__bf16)c1.x; u[5]=(__bf16)c1.y; u[6]=(__bf16)c1.z; u[7]=(__bf16)c1.w; \
            DST[g * 2 + nf] = u;                                      \
        }                                                             \
} while (0)

#define CLUSTER(B_, KC) do {                                          \
    const int kb = (KC) * 32 + lg * 8;                                \
    bf16x8 a0x = *(const bf16x8*)(xt + (0 * 16 + lr) * PITCH + kb);   \
    bf16x8 a0h = *(const bf16x8*)(ht + (0 * 16 + lr) * PITCH + kb);   \
    bf16x8 a1x = *(const bf16x8*)(xt + (1 * 16 + lr) * PITCH + kb);   \
    bf16x8 a1h = *(const bf16x8*)(ht + (1 * 16 + lr) * PITCH + kb);   \
    MFMA12(0, a0x, a0h, B_);                                          \
    a0x = *(const bf16x8*)(xt + (2 * 16 + lr) * PITCH + kb);          \
    a0h = *(const bf16x8*)(ht + (2 * 16 + lr) * PITCH + kb);          \
    MFMA12(1, a1x, a1h, B_);                                          \
    a1x = *(const bf16x8*)(xt + (3 * 16 + lr) * PITCH + kb);          \
    a1h = *(const bf16x8*)(ht + (3 * 16 + lr) * PITCH + kb);          \
    MFMA12(2, a0x, a0h, B_);                                          \
    MFMA12(3, a1x, a1h, B_);                                          \
} while (0)

// ---- fused GRU cell, ablation harness ---------------------------------------
// V0: full (R7 path, real output).  V1: no x/h staging.  V2: no per-K B loads.
// V3: no fused epilogue (raw acc store).  V4: MFMA skeleton only.
template<bool PACKED, int V>
__global__ void __launch_bounds__(512, 2) gru_fused(
    const float* __restrict__ x,  const float* __restrict__ h,
    const __bf16* __restrict__ wb,
    const float* __restrict__ w_ir, const float* __restrict__ w_iz,
    const float* __restrict__ w_in, const float* __restrict__ w_hz,
    const float* __restrict__ w_hn,
    const float* __restrict__ b_ir, const float* __restrict__ b_iz,
    const float* __restrict__ b_in, const float* __restrict__ b_hz,
    const float* __restrict__ b_hn,
    float* __restrict__ out)
{
    constexpr bool DO_STAGE = (V != 1) && (V != 4);
    constexpr bool DO_B     = (V != 2) && (V != 4);
    constexpr bool DO_EPI   = (V != 3) && (V != 4);

    __shared__ __bf16 xt[BM * PITCH];   // 33 KB
    __shared__ __bf16 ht[BM * PITCH];   // 33 KB

    const int t    = threadIdx.x;
    const int row0 = blockIdx.x * BM;
    const int lane = t & 63;
    const int wn   = t >> 6;
    const int lr   = lane & 15;
    const int lg   = lane >> 4;

    const float* wsrc[5] = { w_ir, w_iz, w_in, w_hz, w_hn };
    const __bf16* wbase = wb + wn * 1024 + lane * 8;

    bf16x8 Ba[10], Bb[10];

    // ---- prologue ----
    if (DO_STAGE) {
        f32x4 vx[8], vh[8];
#pragma unroll
        for (int i = 0; i < 8; ++i) {
            int c = i * 512 + t, r = c >> 6, k4 = (c & 63) * 4;
            vx[i] = __builtin_nontemporal_load((const f32x4*)(x + (size_t)(row0 + r) * HID + k4));
            vh[i] = __builtin_nontemporal_load((const f32x4*)(h + (size_t)(row0 + r) * HID + k4));
        }
        if (PACKED && DO_B) LOADB(Ba, wn);
#pragma unroll
        for (int i = 0; i < 8; ++i) {
            int c = i * 512 + t, r = c >> 6, k4 = (c & 63) * 4;
            bf16x4 bx, bh;
            bx[0]=(__bf16)vx[i][0]; bx[1]=(__bf16)vx[i][1]; bx[2]=(__bf16)vx[i][2]; bx[3]=(__bf16)vx[i][3];
            bh[0]=(__bf16)vh[i][0]; bh[1]=(__bf16)vh[i][1]; bh[2]=(__bf16)vh[i][2]; bh[3]=(__bf16)vh[i][3];
            *(bf16x4*)(xt + r * PITCH + k4) = bx;
            *(bf16x4*)(ht + r * PITCH + k4) = bh;
        }
    } else {
        if (PACKED && DO_B) LOADB(Ba, wn);
    }
    if (PACKED && !DO_B) { LOADB(Ba, 0); LOADB(Bb, 1); }   // one-time init only
    __syncthreads();

    f32x4 az[4][2], ar[4][2], anx[4][2], anh[4][2];
#pragma unroll
    for (int mf = 0; mf < 4; ++mf)
#pragma unroll
        for (int nf = 0; nf < 2; ++nf) {
            az[mf][nf] = (f32x4)0.0f; ar[mf][nf] = (f32x4)0.0f;
            anx[mf][nf] = (f32x4)0.0f; anh[mf][nf] = (f32x4)0.0f;
        }

    // ---- K loop: 4 pairs, static Ba/Bb double-buffer ----
#pragma unroll
    for (int i2 = 0; i2 < 4; ++i2) {
        const int kA = (wn + 2 * i2)     & 7;
        const int kB = (wn + 2 * i2 + 1) & 7;
        const int kN = (wn + 2 * i2 + 2) & 7;
        if (PACKED) { if (DO_B) LOADB(Bb, kB); } else LOADB_SLOW(Ba, kA);
        CLUSTER(Ba, kA);
        if (PACKED) { if (DO_B && i2 < 3) LOADB(Ba, kN); } else LOADB_SLOW(Bb, kB);
        CLUSTER(Bb, kB);
    }

    // ---- epilogue ----
    if (DO_EPI) {
        float bz[2], br[2], bnx[2], bnh[2];
#pragma unroll
        for (int nf = 0; nf < 2; ++nf) {
            int col = wn * 32 + nf * 16 + lr;
            bz[nf]  = b_iz[col] + b_hz[col];
            br[nf]  = b_ir[col] + b_hz[col];
            bnx[nf] = b_in[col];
            bnh[nf] = b_hn[col];
        }
#pragma unroll
        for (int mf = 0; mf < 4; ++mf)
#pragma unroll
            for (int nf = 0; nf < 2; ++nf)
#pragma unroll
                for (int i = 0; i < 4; ++i) {
                    int rl  = mf * 16 + lg * 4 + i;
                    int col = wn * 32 + nf * 16 + lr;
                    float z  = 1.0f / (1.0f + __expf(-(az[mf][nf][i] + bz[nf])));
                    float r  = 1.0f / (1.0f + __expf(-(ar[mf][nf][i] + br[nf])));
                    float e2 = __expf(2.0f * (anx[mf][nf][i] + bnx[nf] + r * (anh[mf][nf][i] + bnh[nf])));
                    float g  = 1.0f - 2.0f / (e2 + 1.0f);
                    float hp = (float)ht[rl * PITCH + col];
                    if (V == 0)
                        __builtin_nontemporal_store((1.0f - z) * g + z * hp,
                                                    out + (size_t)(row0 + rl) * HID + col);
                    else
                        out[t * 32 + mf * 8 + nf * 4 + i] = (1.0f - z) * g + z * hp;
                }
    } else {
        // raw acc store into scratch window: depends on ALL acc sets -> nothing DCE'd
#pragma unroll
        for (int mf = 0; mf < 4; ++mf)
#pragma unroll
            for (int nf = 0; nf < 2; ++nf)
#pragma unroll
                for (int i = 0; i < 4; ++i)
                    out[t * 32 + mf * 8 + nf * 4 + i] =
                        az[mf][nf][i] + ar[mf][nf][i] + anx[mf][nf][i] + anh[mf][nf][i];
    }
}

extern "C" void kernel_launch(void* const* d_in, const int* in_sizes, int n_in,
                              void* d_out, int out_size, void* d_ws, size_t ws_size,
                              hipStream_t stream) {
    const float* x    = (const float*)d_in[0];
    const float* h    = (const float*)d_in[1];
    const float* w_ir = (const float*)d_in[2];
    const float* b_ir = (const float*)d_in[3];
    const float* w_iz = (const float*)d_in[4];
    const float* b_iz = (const float*)d_in[5];
    const float* w_in = (const float*)d_in[6];
    const float* b_in = (const float*)d_in[7];
    const float* w_hz = (const float*)d_in[8];
    const float* b_hz = (const float*)d_in[9];
    const float* w_hn = (const float*)d_in[10];
    const float* b_hn = (const float*)d_in[11];
    float* out = (float*)d_out;

    const int B = in_sizes[0] / HID;                                  // 65536
    const size_t wb_bytes = (size_t)5 * HID * HID * sizeof(__bf16);   // 640 KB
    const size_t scratch_need = wb_bytes + (size_t)512 * 32 * 4 + 256; // +64KB window

    if (ws_size >= scratch_need) {
        __bf16* wb   = (__bf16*)d_ws;
        float* wsout = (float*)((char*)d_ws + ((wb_bytes + 255) & ~(size_t)255));
        prepack_frag<<<160, 256, 0, stream>>>(w_ir, w_iz, w_in, w_hz, w_hn, wb);
        // V0: real output
        gru_fused<true, 0><<<B / BM, 512, 0, stream>>>(
            x, h, wb, nullptr, nullptr, nullptr, nullptr, nullptr,
            b_ir, b_iz, b_in, b_hz, b_hn, out);
        // ablation dispatches: garbage into ws window
        gru_fused<true, 1><<<B / BM, 512, 0, stream>>>(
            x, h, wb, nullptr, nullptr, nullptr, nullptr, nullptr,
            b_ir, b_iz, b_in, b_hz, b_hn, wsout);
        gru_fused<true, 2><<<B / BM, 512, 0, stream>>>(
            x, h, wb, nullptr, nullptr, nullptr, nullptr, nullptr,
            b_ir, b_iz, b_in, b_hz, b_hn, wsout);
        gru_fused<true, 3><<<B / BM, 512, 0, stream>>>(
            x, h, wb, nullptr, nullptr, nullptr, nullptr, nullptr,
            b_ir, b_iz, b_in, b_hz, b_hn, wsout);
        gru_fused<true, 4><<<B / BM, 512, 0, stream>>>(
            x, h, wb, nullptr, nullptr, nullptr, nullptr, nullptr,
            b_ir, b_iz, b_in, b_hz, b_hn, wsout);
    } else {
        gru_fused<false, 0><<<B / BM, 512, 0, stream>>>(
            x, h, nullptr, w_ir, w_iz, w_in, w_hz, w_hn,
            b_ir, b_iz, b_in, b_hz, b_hn, out);
    }
}

// Round 10
// 224.762 us; speedup vs baseline: 1.6554x; 1.6554x over previous
//
#include <hip/hip_runtime.h>
#include <hip/hip_bf16.h>

typedef __bf16 bf16x8 __attribute__((ext_vector_type(8)));
typedef __bf16 bf16x4 __attribute__((ext_vector_type(4)));
typedef float  f32x4  __attribute__((ext_vector_type(4)));

#define HID   256
#define BM    64
#define PITCH 264   // bf16 elems per LDS row (16B-aligned; 528B stride -> ~2-way banks)

// gate order: 0=ir 1=iz 2=in 3=hz 4=hn
// ---- prepack weights fp32 -> bf16 in MFMA-fragment order --------------------
__global__ void __launch_bounds__(256) prepack_frag(
    const float* __restrict__ w0, const float* __restrict__ w1,
    const float* __restrict__ w2, const float* __restrict__ w3,
    const float* __restrict__ w4, __bf16* __restrict__ wb)
{
    int t    = blockIdx.x * 256 + threadIdx.x;   // 40960 total
    int lane = t & 63;
    int cb   = (t >> 6) & 15;
    int gk   = t >> 10;                          // ks*5 + g
    int g    = gk % 5;
    int ks   = gk / 5;
    const float* W = g == 0 ? w0 : g == 1 ? w1 : g == 2 ? w2 : g == 3 ? w3 : w4;
    int row = cb * 16 + (lane & 15);
    int k0  = ks * 32 + (lane >> 4) * 8;
    float4 p = *(const float4*)(W + row * HID + k0);
    float4 q = *(const float4*)(W + row * HID + k0 + 4);
    bf16x8 o;
    o[0]=(__bf16)p.x; o[1]=(__bf16)p.y; o[2]=(__bf16)p.z; o[3]=(__bf16)p.w;
    o[4]=(__bf16)q.x; o[5]=(__bf16)q.y; o[6]=(__bf16)q.z; o[7]=(__bf16)q.w;
    *(bf16x8*)(wb + (size_t)t * 8) = o;
}

#define MFMA1(D, A_, B_) D = __builtin_amdgcn_mfma_f32_16x16x32_bf16(A_, B_, D, 0, 0, 0)

#define MFMA12(MF, AX, AH, B_) do {                                   \
    _Pragma("unroll")                                                 \
    for (int nf = 0; nf < 2; ++nf) {                                  \
        MFMA1(az[MF][nf],  AX, B_[2 + nf]);                           \
        MFMA1(ar[MF][nf],  AX, B_[0 + nf]);                           \
        MFMA1(anx[MF][nf], AX, B_[4 + nf]);                           \
        MFMA1(az[MF][nf],  AH, B_[6 + nf]);                           \
        MFMA1(ar[MF][nf],  AH, B_[6 + nf]);                           \
        MFMA1(anh[MF][nf], AH, B_[8 + nf]);                           \
    }                                                                 \
} while (0)

#define LOADB(DST, KK) do {                                           \
    _Pragma("unroll")                                                 \
    for (int g = 0; g < 5; ++g)                                       \
        _Pragma("unroll")                                             \
        for (int nf = 0; nf < 2; ++nf)                                \
            DST[g * 2 + nf] =                                         \
                *(const bf16x8*)(wbase + ((KK) * 5 + g) * 8192 + nf * 512); \
} while (0)

#define LOADB_SLOW(DST, KK) do {                                      \
    _Pragma("unroll")                                                 \
    for (int g = 0; g < 5; ++g)                                       \
        _Pragma("unroll")                                             \
        for (int nf = 0; nf < 2; ++nf) {                              \
            const float* pp = wsrc[g] + ((wn * 2 + nf) * 16 + lr) * HID + (KK) * 32 + lg * 8; \
            float4 c0 = *(const float4*)(pp), c1 = *(const float4*)(pp + 4); \
            bf16x8 u;                                                 \
            u[0]=(__bf16)c0.x; u[1]=(__bf16)c0.y; u[2]=(__bf16)c0.z; u[3]=(__bf16)c0.w; \
            u[4]=(__bf16)c1.x; u[5]=(__bf16)c1.y; u[6]=(__bf16)c1.z; u[7]=(__bf16)c1.w; \
            DST[g * 2 + nf] = u;                                      \
        }                                                             \
} while (0)

#define CLUSTER(XT, HT, B_, KC) do {                                  \
    const int kb = (KC) * 32 + lg * 8;                                \
    bf16x8 a0x = *(const bf16x8*)((XT) + (0 * 16 + lr) * PITCH + kb); \
    bf16x8 a0h = *(const bf16x8*)((HT) + (0 * 16 + lr) * PITCH + kb); \
    bf16x8 a1x = *(const bf16x8*)((XT) + (1 * 16 + lr) * PITCH + kb); \
    bf16x8 a1h = *(const bf16x8*)((HT) + (1 * 16 + lr) * PITCH + kb); \
    MFMA12(0, a0x, a0h, B_);                                          \
    a0x = *(const bf16x8*)((XT) + (2 * 16 + lr) * PITCH + kb);        \
    a0h = *(const bf16x8*)((HT) + (2 * 16 + lr) * PITCH + kb);        \
    MFMA12(1, a1x, a1h, B_);                                          \
    a1x = *(const bf16x8*)((XT) + (3 * 16 + lr) * PITCH + kb);        \
    a1h = *(const bf16x8*)((HT) + (3 * 16 + lr) * PITCH + kb);        \
    MFMA12(2, a0x, a0h, B_);                                          \
    MFMA12(3, a1x, a1h, B_);                                          \
} while (0)

// K-step S: prefetch B for step S+1 into BNXT, compute BCUR at k=(wn+S)&7.
// At S==7 the prefetch wraps to wn == NEXT TILE's first set (weights are
// tile-invariant) -> the B pipeline never drains across tiles.
#define KSTEP(XT, HT, S, BCUR, BNXT) do {                             \
    const int kc = (wn + (S)) & 7;                                    \
    const int kn = (wn + (S) + 1) & 7;                                \
    if (PACKED) LOADB(BNXT, kn); else LOADB_SLOW(BCUR, kc);           \
    CLUSTER(XT, HT, BCUR, kc);                                        \
} while (0)

// prefetch chunk C (8 rows) of next tile: issue (8 regs in flight), lag-1 store
#define PFI(C) do {                                                   \
    int r  = (C) * 8 + (t >> 6);                                      \
    int k4 = (t & 63) * 4;                                            \
    px = __builtin_nontemporal_load((const f32x4*)(x + (prow0 + r) * HID + k4)); \
    ph = __builtin_nontemporal_load((const f32x4*)(h + (prow0 + r) * HID + k4)); \
} while (0)

#define PFS(XW, HW, C) do {                                           \
    int r  = (C) * 8 + (t >> 6);                                      \
    int k4 = (t & 63) * 4;                                            \
    bf16x4 bx, bh;                                                    \
    bx[0]=(__bf16)px[0]; bx[1]=(__bf16)px[1]; bx[2]=(__bf16)px[2]; bx[3]=(__bf16)px[3]; \
    bh[0]=(__bf16)ph[0]; bh[1]=(__bf16)ph[1]; bh[2]=(__bf16)ph[2]; bh[3]=(__bf16)ph[3]; \
    *(bf16x4*)((XW) + r * PITCH + k4) = bx;                           \
    *(bf16x4*)((HW) + r * PITCH + k4) = bh;                           \
} while (0)

// full tile: K-loop on (XT,HT) with next tile's staging woven in (-> XW,HW),
// then fused-gate epilogue for TILE.
#define TILE_BODY(XT, HT, XW, HW, TILE, PFC) do {                     \
    const bool pf_  = (PFC);                                          \
    const int prow0 = ((TILE) + 1) * BM;                              \
    f32x4 px, ph;                                                     \
    _Pragma("unroll")                                                 \
    for (int mf = 0; mf < 4; ++mf)                                    \
        _Pragma("unroll")                                             \
        for (int nf = 0; nf < 2; ++nf) {                              \
            az[mf][nf] = (f32x4)0.0f; ar[mf][nf] = (f32x4)0.0f;       \
            anx[mf][nf] = (f32x4)0.0f; anh[mf][nf] = (f32x4)0.0f;     \
        }                                                             \
    if (pf_) PFI(0);                                                  \
    KSTEP(XT, HT, 0, Ba, Bb); if (pf_) { PFS(XW, HW, 0); PFI(1); }    \
    KSTEP(XT, HT, 1, Bb, Ba); if (pf_) { PFS(XW, HW, 1); PFI(2); }    \
    KSTEP(XT, HT, 2, Ba, Bb); if (pf_) { PFS(XW, HW, 2); PFI(3); }    \
    KSTEP(XT, HT, 3, Bb, Ba); if (pf_) { PFS(XW, HW, 3); PFI(4); }    \
    KSTEP(XT, HT, 4, Ba, Bb); if (pf_) { PFS(XW, HW, 4); PFI(5); }    \
    KSTEP(XT, HT, 5, Bb, Ba); if (pf_) { PFS(XW, HW, 5); PFI(6); }    \
    KSTEP(XT, HT, 6, Ba, Bb); if (pf_) { PFS(XW, HW, 6); PFI(7); }    \
    KSTEP(XT, HT, 7, Bb, Ba); if (pf_) { PFS(XW, HW, 7); }            \
    const int row0 = (TILE) * BM;                                     \
    _Pragma("unroll")                                                 \
    for (int mf = 0; mf < 4; ++mf)                                    \
        _Pragma("unroll")                                             \
        for (int nf = 0; nf < 2; ++nf)                                \
            _Pragma("unroll")                                         \
            for (int i = 0; i < 4; ++i) {                             \
                int rl  = mf * 16 + lg * 4 + i;                       \
                int col = wn * 32 + nf * 16 + lr;                     \
                float z  = 1.0f / (1.0f + __expf(-(az[mf][nf][i] + bz[nf]))); \
                float r  = 1.0f / (1.0f + __expf(-(ar[mf][nf][i] + br[nf]))); \
                float e2 = __expf(2.0f * (anx[mf][nf][i] + bnx[nf] + r * (anh[mf][nf][i] + bnh[nf]))); \
                float g  = 1.0f - 2.0f / (e2 + 1.0f);                 \
                float hp = (float)(HT)[rl * PITCH + col];             \
                __builtin_nontemporal_store((1.0f - z) * g + z * hp,  \
                    out + (size_t)(row0 + rl) * HID + col);           \
            }                                                         \
} while (0)

// ---- fused GRU cell ---------------------------------------------------------
// Persistent: 256 blocks x 4 contiguous BM=64 tiles. Two named LDS buffer
// pairs alternate at COMPILE TIME; tile T+1's x/h staging (8 chunks, 8 regs
// in flight) is interleaved with tile T's K-steps. One barrier per tile.
template<bool PACKED>
__global__ void __launch_bounds__(512, 2) gru_fused(
    const float* __restrict__ x,  const float* __restrict__ h,
    const __bf16* __restrict__ wb,
    const float* __restrict__ w_ir, const float* __restrict__ w_iz,
    const float* __restrict__ w_in, const float* __restrict__ w_hz,
    const float* __restrict__ w_hn,
    const float* __restrict__ b_ir, const float* __restrict__ b_iz,
    const float* __restrict__ b_in, const float* __restrict__ b_hz,
    const float* __restrict__ b_hn,
    float* __restrict__ out)
{
    __shared__ __bf16 xt0[BM * PITCH];   // 4 x 33 KB = 132 KB
    __shared__ __bf16 ht0[BM * PITCH];
    __shared__ __bf16 xt1[BM * PITCH];
    __shared__ __bf16 ht1[BM * PITCH];

    const int t    = threadIdx.x;
    const int lane = t & 63;
    const int wn   = t >> 6;      // 0..7 : col slice AND K-start stagger
    const int lr   = lane & 15;
    const int lg   = lane >> 4;
    const int tileBase = blockIdx.x * 4;

    const float* wsrc[5] = { w_ir, w_iz, w_in, w_hz, w_hn };
    const __bf16* wbase = wb + wn * 1024 + lane * 8;

    bf16x8 Ba[10], Bb[10];
    f32x4 az[4][2], ar[4][2], anx[4][2], anh[4][2];   // 128 accs

    // ---- biases (tile-invariant) --------------------------------------------
    float bz[2], br[2], bnx[2], bnh[2];
#pragma unroll
    for (int nf = 0; nf < 2; ++nf) {
        int col = wn * 32 + nf * 16 + lr;
        bz[nf]  = b_iz[col] + b_hz[col];
        br[nf]  = b_ir[col] + b_hz[col];
        bnx[nf] = b_in[col];
        bnh[nf] = b_hn[col];
    }

    // ---- bulk-stage first tile into buf0 (cold start, high MLP) -------------
    {
        const int row0 = tileBase * BM;
        f32x4 vx[8], vh[8];
#pragma unroll
        for (int i = 0; i < 8; ++i) {
            int c = i * 512 + t, r = c >> 6, k4 = (c & 63) * 4;
            vx[i] = __builtin_nontemporal_load((const f32x4*)(x + (row0 + r) * HID + k4));
            vh[i] = __builtin_nontemporal_load((const f32x4*)(h + (row0 + r) * HID + k4));
        }
        if (PACKED) LOADB(Ba, wn);    // prime the B pipeline (K-step wn)
#pragma unroll
        for (int i = 0; i < 8; ++i) {
            int c = i * 512 + t, r = c >> 6, k4 = (c & 63) * 4;
            bf16x4 bx, bh;
            bx[0]=(__bf16)vx[i][0]; bx[1]=(__bf16)vx[i][1]; bx[2]=(__bf16)vx[i][2]; bx[3]=(__bf16)vx[i][3];
            bh[0]=(__bf16)vh[i][0]; bh[1]=(__bf16)vh[i][1]; bh[2]=(__bf16)vh[i][2]; bh[3]=(__bf16)vh[i][3];
            *(bf16x4*)(xt0 + r * PITCH + k4) = bx;
            *(bf16x4*)(ht0 + r * PITCH + k4) = bh;
        }
    }
    __syncthreads();

    // ---- 4 tiles: compile-time buffer alternation ---------------------------
    for (int it = 0; it < 2; ++it) {
        const int tE = tileBase + it * 2;
        TILE_BODY(xt0, ht0, xt1, ht1, tE, true);
        __syncthreads();
        TILE_BODY(xt1, ht1, xt0, ht0, tE + 1, it == 0);
        __syncthreads();
    }
}

extern "C" void kernel_launch(void* const* d_in, const int* in_sizes, int n_in,
                              void* d_out, int out_size, void* d_ws, size_t ws_size,
                              hipStream_t stream) {
    const float* x    = (const float*)d_in[0];
    const float* h    = (const float*)d_in[1];
    const float* w_ir = (const float*)d_in[2];
    const float* b_ir = (const float*)d_in[3];
    const float* w_iz = (const float*)d_in[4];
    const float* b_iz = (const float*)d_in[5];
    const float* w_in = (const float*)d_in[6];
    const float* b_in = (const float*)d_in[7];
    const float* w_hz = (const float*)d_in[8];
    const float* b_hz = (const float*)d_in[9];
    const float* w_hn = (const float*)d_in[10];
    const float* b_hn = (const float*)d_in[11];
    float* out = (float*)d_out;

    const int B      = in_sizes[0] / HID;                             // 65536
    const int nblk   = (B / BM) / 4;                                  // 256
    const size_t wb_bytes = (size_t)5 * HID * HID * sizeof(__bf16);   // 640 KB

    if (ws_size >= wb_bytes) {
        __bf16* wb = (__bf16*)d_ws;
        prepack_frag<<<160, 256, 0, stream>>>(w_ir, w_iz, w_in, w_hz, w_hn, wb);
        gru_fused<true><<<nblk, 512, 0, stream>>>(
            x, h, wb, nullptr, nullptr, nullptr, nullptr, nullptr,
            b_ir, b_iz, b_in, b_hz, b_hn, out);
    } else {
        gru_fused<false><<<nblk, 512, 0, stream>>>(
            x, h, nullptr, w_ir, w_iz, w_in, w_hz, w_hn,
            b_ir, b_iz, b_in, b_hz, b_hn, out);
    }
}

// Round 11
// 219.542 us; speedup vs baseline: 1.6947x; 1.0238x over previous
//
#include <hip/hip_runtime.h>
#include <hip/hip_bf16.h>

typedef __bf16 bf16x8 __attribute__((ext_vector_type(8)));
typedef __bf16 bf16x4 __attribute__((ext_vector_type(4)));
typedef float  f32x4  __attribute__((ext_vector_type(4)));

#define HID   256
#define BM    32
#define PITCH 264   // bf16 elems per LDS row
#define TPB   8     // tiles per block (persistent)

// gate order: 0=ir 1=iz 2=in 3=hz 4=hn
// ---- prepack weights fp32 -> bf16 in MFMA-fragment order --------------------
// fragment (ks,g,cb): lane l, elem j = W_g[cb*16 + (l&15)][ks*32 + (l>>4)*8 + j]
// stored at wb[((ks*5+g)*16+cb)*512 + l*8 + j]
__global__ void __launch_bounds__(256) prepack_frag(
    const float* __restrict__ w0, const float* __restrict__ w1,
    const float* __restrict__ w2, const float* __restrict__ w3,
    const float* __restrict__ w4, __bf16* __restrict__ wb)
{
    int t    = blockIdx.x * 256 + threadIdx.x;   // 40960 total
    int lane = t & 63;
    int cb   = (t >> 6) & 15;
    int gk   = t >> 10;                          // ks*5 + g
    int g    = gk % 5;
    int ks   = gk / 5;
    const float* W = g == 0 ? w0 : g == 1 ? w1 : g == 2 ? w2 : g == 3 ? w3 : w4;
    int row = cb * 16 + (lane & 15);
    int k0  = ks * 32 + (lane >> 4) * 8;
    float4 p = *(const float4*)(W + row * HID + k0);
    float4 q = *(const float4*)(W + row * HID + k0 + 4);
    bf16x8 o;
    o[0]=(__bf16)p.x; o[1]=(__bf16)p.y; o[2]=(__bf16)p.z; o[3]=(__bf16)p.w;
    o[4]=(__bf16)q.x; o[5]=(__bf16)q.y; o[6]=(__bf16)q.z; o[7]=(__bf16)q.w;
    *(bf16x8*)(wb + (size_t)t * 8) = o;
}

#define MFMA1(D, A_, B_) D = __builtin_amdgcn_mfma_f32_16x16x32_bf16(A_, B_, D, 0, 0, 0)

// async global->LDS, 16B per lane, wave-uniform LDS base
#define G2L(SRC, DST) \
    __builtin_amdgcn_global_load_lds( \
        (const __attribute__((address_space(1))) void*)(SRC), \
        (__attribute__((address_space(3))) void*)(DST), 16, 0, 0)

// stage {ir,in,hn} of K-step KS into lbo (48KB). wave wn: chunks c = wn+8*it.
#define STAGE_BO(KS) do {                                               \
    _Pragma("unroll")                                                   \
    for (int it = 0; it < 6; ++it) {                                    \
        int c = wn + it * 8;            /* 0..47, 1KB chunks */         \
        int gsel = c >> 4;                                              \
        int gate = gsel == 0 ? 0 : gsel == 1 ? 2 : 4;                   \
        G2L(wb + ((KS) * 5 + gate) * 8192 + (c & 15) * 512 + lane * 8,  \
            lbo + c * 512);                                             \
    }                                                                   \
} while (0)

// stage {iz,hz} of K-step KS into lbz (32KB)
#define STAGE_BZ(KS) do {                                               \
    _Pragma("unroll")                                                   \
    for (int it = 0; it < 4; ++it) {                                    \
        int c = wn + it * 8;            /* 0..31 */                     \
        int gate = (c >> 4) ? 3 : 1;                                    \
        G2L(wb + ((KS) * 5 + gate) * 8192 + (c & 15) * 512 + lane * 8,  \
            lbz + c * 512);                                             \
    }                                                                   \
} while (0)

#define CVT8(DST, PP) do {                                              \
    float4 c0_ = *(const float4*)(PP), c1_ = *(const float4*)((PP) + 4);\
    DST[0]=(__bf16)c0_.x; DST[1]=(__bf16)c0_.y; DST[2]=(__bf16)c0_.z; DST[3]=(__bf16)c0_.w; \
    DST[4]=(__bf16)c1_.x; DST[5]=(__bf16)c1_.y; DST[6]=(__bf16)c1_.z; DST[7]=(__bf16)c1_.w; \
} while (0)

// slow fallbacks (unpacked weights): reg-convert into the same LDS layout
#define STAGE_BO_SLOW(KS) do {                                          \
    _Pragma("unroll")                                                   \
    for (int it = 0; it < 6; ++it) {                                    \
        int c = wn + it * 8;                                            \
        int gsel = c >> 4;                                              \
        const float* W_ = gsel == 0 ? w_ir : gsel == 1 ? w_in : w_hn;   \
        int row = (c & 15) * 16 + (lane & 15);                          \
        const float* pp = W_ + row * HID + (KS) * 32 + (lane >> 4) * 8; \
        bf16x8 u; CVT8(u, pp);                                          \
        *(bf16x8*)(lbo + c * 512 + lane * 8) = u;                       \
    }                                                                   \
} while (0)

#define STAGE_BZ_SLOW(KS) do {                                          \
    _Pragma("unroll")                                                   \
    for (int it = 0; it < 4; ++it) {                                    \
        int c = wn + it * 8;                                            \
        const float* W_ = (c >> 4) ? w_hz : w_iz;                       \
        int row = (c & 15) * 16 + (lane & 15);                          \
        const float* pp = W_ + row * HID + (KS) * 32 + (lane >> 4) * 8; \
        bf16x8 u; CVT8(u, pp);                                          \
        *(bf16x8*)(lbz + c * 512 + lane * 8) = u;                       \
    }                                                                   \
} while (0)

// next-tile x/h prefetch: chunk C = rows C*8..C*8+7 (8 regs in flight)
#define PFI(C) do {                                                     \
    int r_  = (C) * 8 + (t >> 6);                                       \
    int k4_ = (t & 63) * 4;                                             \
    px = __builtin_nontemporal_load((const f32x4*)(x + (size_t)(prow0 + r_) * HID + k4_)); \
    ph = __builtin_nontemporal_load((const f32x4*)(h + (size_t)(prow0 + r_) * HID + k4_)); \
} while (0)

#define PFS(XW, HW, C) do {                                             \
    int r_  = (C) * 8 + (t >> 6);                                       \
    int k4_ = (t & 63) * 4;                                             \
    bf16x4 bx_, bh_;                                                    \
    bx_[0]=(__bf16)px[0]; bx_[1]=(__bf16)px[1]; bx_[2]=(__bf16)px[2]; bx_[3]=(__bf16)px[3]; \
    bh_[0]=(__bf16)ph[0]; bh_[1]=(__bf16)ph[1]; bh_[2]=(__bf16)ph[2]; bh_[3]=(__bf16)ph[3]; \
    *(bf16x4*)((XW) + r_ * PITCH + k4_) = bx_;                          \
    *(bf16x4*)((HW) + r_ * PITCH + k4_) = bh_;                          \
} while (0)

// one tile: 8 K-steps x 2 phases (A: az from lbz while lbo stages;
//           B: ar/anx/anh from lbo while lbz(ks+1) stages)
#define TILE_BODY(XT, HT, XW, HW, TILE, PF) do {                        \
    const bool pf_ = (PF);                                              \
    const size_t prow0 = (size_t)((TILE) + 1) * BM;                     \
    f32x4 px, ph;                                                       \
    f32x4 az[2][2], ar[2][2], anx[2][2], anh[2][2];                     \
    _Pragma("unroll")                                                   \
    for (int mf = 0; mf < 2; ++mf)                                      \
        _Pragma("unroll")                                               \
        for (int nf = 0; nf < 2; ++nf) {                                \
            az[mf][nf] = (f32x4)0.0f; ar[mf][nf] = (f32x4)0.0f;         \
            anx[mf][nf] = (f32x4)0.0f; anh[mf][nf] = (f32x4)0.0f;       \
        }                                                               \
    _Pragma("unroll")                                                   \
    for (int ks = 0; ks < 8; ++ks) {                                    \
        /* ---------- phase A ---------- */                             \
        if (PACKED) STAGE_BO(ks); else STAGE_BO_SLOW(ks);               \
        if (pf_) {                                                      \
            if (ks >= 1 && ks <= 4) PFS(XW, HW, ks - 1);                \
            if (ks < 4) PFI(ks);                                        \
        }                                                               \
        const int kb = ks * 32 + lg * 8;                                \
        bf16x8 ax0 = *(const bf16x8*)((XT) + lr * PITCH + kb);          \
        bf16x8 ax1 = *(const bf16x8*)((XT) + (16 + lr) * PITCH + kb);   \
        bf16x8 ah0 = *(const bf16x8*)((HT) + lr * PITCH + kb);          \
        bf16x8 ah1 = *(const bf16x8*)((HT) + (16 + lr) * PITCH + kb);   \
        bf16x8 biz[2], bhz[2];                                          \
        _Pragma("unroll")                                               \
        for (int nf = 0; nf < 2; ++nf) {                                \
            biz[nf] = *(const bf16x8*)(lbz + (wn * 2 + nf) * 512 + lane * 8);        \
            bhz[nf] = *(const bf16x8*)(lbz + 8192 + (wn * 2 + nf) * 512 + lane * 8); \
        }                                                               \
        _Pragma("unroll")                                               \
        for (int nf = 0; nf < 2; ++nf) { MFMA1(az[0][nf], ax0, biz[nf]); MFMA1(az[1][nf], ax1, biz[nf]); } \
        _Pragma("unroll")                                               \
        for (int nf = 0; nf < 2; ++nf) { MFMA1(az[0][nf], ah0, bhz[nf]); MFMA1(az[1][nf], ah1, bhz[nf]); } \
        __syncthreads();                                                \
        /* ---------- phase B ---------- */                             \
        if (PACKED) STAGE_BZ((ks + 1) & 7); else STAGE_BZ_SLOW((ks + 1) & 7); \
        bf16x8 bir[2], bin[2], bhn[2];                                  \
        _Pragma("unroll")                                               \
        for (int nf = 0; nf < 2; ++nf) {                                \
            bir[nf] = *(const bf16x8*)(lbo + (wn * 2 + nf) * 512 + lane * 8);         \
            bin[nf] = *(const bf16x8*)(lbo + 8192 + (wn * 2 + nf) * 512 + lane * 8);  \
            bhn[nf] = *(const bf16x8*)(lbo + 16384 + (wn * 2 + nf) * 512 + lane * 8); \
        }                                                               \
        _Pragma("unroll")                                               \
        for (int nf = 0; nf < 2; ++nf) { MFMA1(ar[0][nf],  ax0, bir[nf]); MFMA1(ar[1][nf],  ax1, bir[nf]); } \
        _Pragma("unroll")                                               \
        for (int nf = 0; nf < 2; ++nf) { MFMA1(anx[0][nf], ax0, bin[nf]); MFMA1(anx[1][nf], ax1, bin[nf]); } \
        _Pragma("unroll")                                               \
        for (int nf = 0; nf < 2; ++nf) { MFMA1(ar[0][nf],  ah0, bhz[nf]); MFMA1(ar[1][nf],  ah1, bhz[nf]); } \
        _Pragma("unroll")                                               \
        for (int nf = 0; nf < 2; ++nf) { MFMA1(anh[0][nf], ah0, bhn[nf]); MFMA1(anh[1][nf], ah1, bhn[nf]); } \
        __syncthreads();                                                \
    }                                                                   \
    /* ---------- epilogue ---------- */                                \
    const size_t row0 = (size_t)(TILE) * BM;                            \
    _Pragma("unroll")                                                   \
    for (int mf = 0; mf < 2; ++mf)                                      \
        _Pragma("unroll")                                               \
        for (int nf = 0; nf < 2; ++nf)                                  \
            _Pragma("unroll")                                           \
            for (int i = 0; i < 4; ++i) {                               \
                int rl  = mf * 16 + lg * 4 + i;                         \
                int col = wn * 32 + nf * 16 + lr;                       \
                float z  = 1.0f / (1.0f + __expf(-(az[mf][nf][i] + bz[nf]))); \
                float r  = 1.0f / (1.0f + __expf(-(ar[mf][nf][i] + br[nf]))); \
                float e2 = __expf(2.0f * (anx[mf][nf][i] + bnx[nf] + r * (anh[mf][nf][i] + bnh[nf]))); \
                float g  = 1.0f - 2.0f / (e2 + 1.0f);                   \
                float hp = (float)(HT)[rl * PITCH + col];               \
                __builtin_nontemporal_store((1.0f - z) * g + z * hp,    \
                    out + (size_t)(row0 + rl) * HID + col);             \
            }                                                           \
} while (0)

// ---- fused GRU cell ---------------------------------------------------------
// 256 persistent blocks x 8 tiles of BM=32. B-weights staged per K-step into
// LDS via global_load_lds (2-phase, shared by all 8 waves); x/h double-buffered
// bf16 in LDS with next-tile chunks woven into phase A. acc = 64 AGPRs.
template<bool PACKED>
__global__ void __launch_bounds__(512, 2) gru_fused(
    const float* __restrict__ x,  const float* __restrict__ h,
    const __bf16* __restrict__ wb,
    const float* __restrict__ w_ir, const float* __restrict__ w_iz,
    const float* __restrict__ w_in, const float* __restrict__ w_hz,
    const float* __restrict__ w_hn,
    const float* __restrict__ b_ir, const float* __restrict__ b_iz,
    const float* __restrict__ b_in, const float* __restrict__ b_hz,
    const float* __restrict__ b_hn,
    float* __restrict__ out)
{
    __shared__ __bf16 xt0[BM * PITCH], ht0[BM * PITCH];   // 2 x 16.9 KB
    __shared__ __bf16 xt1[BM * PITCH], ht1[BM * PITCH];   // 2 x 16.9 KB
    __shared__ __bf16 lbz[16384];                         // {iz,hz}   32 KB
    __shared__ __bf16 lbo[24576];                         // {ir,in,hn} 48 KB

    const int t    = threadIdx.x;
    const int lane = t & 63;
    const int wn   = t >> 6;      // 0..7 : col slice
    const int lr   = lane & 15;
    const int lg   = lane >> 4;

    // biases (tile-invariant)
    float bz[2], br[2], bnx[2], bnh[2];
#pragma unroll
    for (int nf = 0; nf < 2; ++nf) {
        int col = wn * 32 + nf * 16 + lr;
        bz[nf]  = b_iz[col] + b_hz[col];
        br[nf]  = b_ir[col] + b_hz[col];
        bnx[nf] = b_in[col];
        bnh[nf] = b_hn[col];
    }

    const int t0 = blockIdx.x * TPB;

    // ---- prologue: stage tile0 x/h into buf0 + BZ(0) ------------------------
    if (PACKED) STAGE_BZ(0); else STAGE_BZ_SLOW(0);
    {
        const size_t row0 = (size_t)t0 * BM;
#pragma unroll
        for (int i = 0; i < 4; ++i) {
            int c = i * 512 + t, r = c >> 6, k4 = (c & 63) * 4;
            f32x4 vx = __builtin_nontemporal_load((const f32x4*)(x + (row0 + r) * HID + k4));
            f32x4 vh = __builtin_nontemporal_load((const f32x4*)(h + (row0 + r) * HID + k4));
            bf16x4 bx, bh;
            bx[0]=(__bf16)vx[0]; bx[1]=(__bf16)vx[1]; bx[2]=(__bf16)vx[2]; bx[3]=(__bf16)vx[3];
            bh[0]=(__bf16)vh[0]; bh[1]=(__bf16)vh[1]; bh[2]=(__bf16)vh[2]; bh[3]=(__bf16)vh[3];
            *(bf16x4*)(xt0 + r * PITCH + k4) = bx;
            *(bf16x4*)(ht0 + r * PITCH + k4) = bh;
        }
    }
    __syncthreads();

    // ---- 8 tiles, compile-time buffer alternation ---------------------------
    int tile = t0;
    for (int it2 = 0; it2 < TPB / 2; ++it2) {
        TILE_BODY(xt0, ht0, xt1, ht1, tile, true);
        ++tile;
        TILE_BODY(xt1, ht1, xt0, ht0, tile, (it2 < TPB / 2 - 1));
        ++tile;
    }
}

extern "C" void kernel_launch(void* const* d_in, const int* in_sizes, int n_in,
                              void* d_out, int out_size, void* d_ws, size_t ws_size,
                              hipStream_t stream) {
    const float* x    = (const float*)d_in[0];
    const float* h    = (const float*)d_in[1];
    const float* w_ir = (const float*)d_in[2];
    const float* b_ir = (const float*)d_in[3];
    const float* w_iz = (const float*)d_in[4];
    const float* b_iz = (const float*)d_in[5];
    const float* w_in = (const float*)d_in[6];
    const float* b_in = (const float*)d_in[7];
    const float* w_hz = (const float*)d_in[8];
    const float* b_hz = (const float*)d_in[9];
    const float* w_hn = (const float*)d_in[10];
    const float* b_hn = (const float*)d_in[11];
    float* out = (float*)d_out;

    const int B    = in_sizes[0] / HID;                               // 65536
    const int nblk = (B / BM) / TPB;                                  // 256
    const size_t wb_bytes = (size_t)5 * HID * HID * sizeof(__bf16);   // 640 KB

    if (ws_size >= wb_bytes) {
        __bf16* wb = (__bf16*)d_ws;
        prepack_frag<<<160, 256, 0, stream>>>(w_ir, w_iz, w_in, w_hz, w_hn, wb);
        gru_fused<true><<<nblk, 512, 0, stream>>>(
            x, h, wb, nullptr, nullptr, nullptr, nullptr, nullptr,
            b_ir, b_iz, b_in, b_hz, b_hn, out);
    } else {
        gru_fused<false><<<nblk, 512, 0, stream>>>(
            x, h, nullptr, w_ir, w_iz, w_in, w_hz, w_hn,
            b_ir, b_iz, b_in, b_hz, b_hn, out);
    }
}

// Round 12
// 131.642 us; speedup vs baseline: 2.8263x; 1.6677x over previous
//
#include <hip/hip_runtime.h>
#include <hip/hip_bf16.h>

typedef __bf16 bf16x8 __attribute__((ext_vector_type(8)));
typedef __bf16 bf16x4 __attribute__((ext_vector_type(4)));
typedef float  f32x4  __attribute__((ext_vector_type(4)));

#define HID   256
#define BM    32
#define PITCH 264   // bf16 elems per LDS row (16B-aligned; ~2-way banks, proven)

// gate order: 0=ir 1=iz 2=in 3=hz 4=hn
// ---- prepack weights fp32 -> bf16 in MFMA-fragment order --------------------
// fragment (ks,g,cb): lane l, elem j = W_g[cb*16 + (l&15)][ks*32 + (l>>4)*8 + j]
// stored at wb[((ks*5+g)*16+cb)*512 + l*8 + j]  -> 1KB contiguous per fragment
__global__ void __launch_bounds__(256) prepack_frag(
    const float* __restrict__ w0, const float* __restrict__ w1,
    const float* __restrict__ w2, const float* __restrict__ w3,
    const float* __restrict__ w4, __bf16* __restrict__ wb)
{
    int t    = blockIdx.x * 256 + threadIdx.x;   // 40960 total
    int lane = t & 63;
    int cb   = (t >> 6) & 15;
    int gk   = t >> 10;                          // ks*5 + g
    int g    = gk % 5;
    int ks   = gk / 5;
    const float* W = g == 0 ? w0 : g == 1 ? w1 : g == 2 ? w2 : g == 3 ? w3 : w4;
    int row = cb * 16 + (lane & 15);
    int k0  = ks * 32 + (lane >> 4) * 8;
    float4 p = *(const float4*)(W + row * HID + k0);
    float4 q = *(const float4*)(W + row * HID + k0 + 4);
    bf16x8 o;
    o[0]=(__bf16)p.x; o[1]=(__bf16)p.y; o[2]=(__bf16)p.z; o[3]=(__bf16)p.w;
    o[4]=(__bf16)q.x; o[5]=(__bf16)q.y; o[6]=(__bf16)q.z; o[7]=(__bf16)q.w;
    *(bf16x8*)(wb + (size_t)t * 8) = o;
}

#define MFMA1(D, A_, B_) D = __builtin_amdgcn_mfma_f32_16x16x32_bf16(A_, B_, D, 0, 0, 0)

#define CVT8(DST, PP) do {                                              \
    float4 c0_ = *(const float4*)(PP), c1_ = *(const float4*)((PP) + 4);\
    DST[0]=(__bf16)c0_.x; DST[1]=(__bf16)c0_.y; DST[2]=(__bf16)c0_.z; DST[3]=(__bf16)c0_.w; \
    DST[4]=(__bf16)c1_.x; DST[5]=(__bf16)c1_.y; DST[6]=(__bf16)c1_.z; DST[7]=(__bf16)c1_.w; \
} while (0)

// one K-step: 4 ds_read_b128 + 12 MFMA, B from resident registers (no loads!)
#define KSTEP(XT, HT, KS) do {                                          \
    const int kb = (KS) * 32 + lg * 8;                                  \
    bf16x8 ax0 = *(const bf16x8*)((XT) + lr * PITCH + kb);              \
    bf16x8 ah0 = *(const bf16x8*)((HT) + lr * PITCH + kb);              \
    bf16x8 ax1 = *(const bf16x8*)((XT) + (16 + lr) * PITCH + kb);       \
    bf16x8 ah1 = *(const bf16x8*)((HT) + (16 + lr) * PITCH + kb);       \
    MFMA1(az[0],  ax0, Breg[KS][1]); MFMA1(az[1],  ax1, Breg[KS][1]);   \
    MFMA1(ar[0],  ax0, Breg[KS][0]); MFMA1(ar[1],  ax1, Breg[KS][0]);   \
    MFMA1(anx[0], ax0, Breg[KS][2]); MFMA1(anx[1], ax1, Breg[KS][2]);   \
    MFMA1(az[0],  ah0, Breg[KS][3]); MFMA1(az[1],  ah1, Breg[KS][3]);   \
    MFMA1(ar[0],  ah0, Breg[KS][3]); MFMA1(ar[1],  ah1, Breg[KS][3]);   \
    MFMA1(anh[0], ah0, Breg[KS][4]); MFMA1(anh[1], ah1, Breg[KS][4]);   \
} while (0)

// next-tile x/h staging: chunk C (0..3), 8 regs in flight, lag store
#define PFI(C) do {                                                     \
    int e_ = (C) * 512 + t, r_ = e_ >> 6, c4_ = (e_ & 63) * 4;          \
    px = __builtin_nontemporal_load((const f32x4*)(x + (prow0 + r_) * HID + c4_)); \
    ph = __builtin_nontemporal_load((const f32x4*)(h + (prow0 + r_) * HID + c4_)); \
} while (0)

#define PFS(XW, HW, C) do {                                             \
    int e_ = (C) * 512 + t, r_ = e_ >> 6, c4_ = (e_ & 63) * 4;          \
    bf16x4 bx_, bh_;                                                    \
    bx_[0]=(__bf16)px[0]; bx_[1]=(__bf16)px[1]; bx_[2]=(__bf16)px[2]; bx_[3]=(__bf16)px[3]; \
    bh_[0]=(__bf16)ph[0]; bh_[1]=(__bf16)ph[1]; bh_[2]=(__bf16)ph[2]; bh_[3]=(__bf16)ph[3]; \
    *(bf16x4*)((XW) + r_ * PITCH + c4_) = bx_;                          \
    *(bf16x4*)((HW) + r_ * PITCH + c4_) = bh_;                          \
} while (0)

// full tile: 8 K-steps (zero global loads) + woven next-tile staging + epilogue
#define TILE_BODY(XT, HT, XW, HW, TILE, PF) do {                        \
    const bool pf_ = (PF);                                              \
    const size_t prow0 = (size_t)((TILE) + 1) * BM;                     \
    f32x4 px, ph;                                                       \
    f32x4 az[2], ar[2], anx[2], anh[2];                                 \
    _Pragma("unroll")                                                   \
    for (int mf = 0; mf < 2; ++mf) {                                    \
        az[mf] = (f32x4)0.0f; ar[mf] = (f32x4)0.0f;                     \
        anx[mf] = (f32x4)0.0f; anh[mf] = (f32x4)0.0f;                   \
    }                                                                   \
    if (pf_) PFI(0);                                                    \
    KSTEP(XT, HT, 0);                                                   \
    KSTEP(XT, HT, 1);                                                   \
    if (pf_) { PFS(XW, HW, 0); PFI(1); }                                \
    KSTEP(XT, HT, 2);                                                   \
    KSTEP(XT, HT, 3);                                                   \
    if (pf_) { PFS(XW, HW, 1); PFI(2); }                                \
    KSTEP(XT, HT, 4);                                                   \
    KSTEP(XT, HT, 5);                                                   \
    if (pf_) { PFS(XW, HW, 2); PFI(3); }                                \
    KSTEP(XT, HT, 6);                                                   \
    KSTEP(XT, HT, 7);                                                   \
    if (pf_) PFS(XW, HW, 3);                                            \
    const size_t row0 = (size_t)(TILE) * BM;                            \
    _Pragma("unroll")                                                   \
    for (int mf = 0; mf < 2; ++mf)                                      \
        _Pragma("unroll")                                               \
        for (int i = 0; i < 4; ++i) {                                   \
            int rl = mf * 16 + lg * 4 + i;                              \
            float z  = 1.0f / (1.0f + __expf(-(az[mf][i] + bz)));       \
            float r  = 1.0f / (1.0f + __expf(-(ar[mf][i] + br)));       \
            float e2 = __expf(2.0f * (anx[mf][i] + bnx + r * (anh[mf][i] + bnh))); \
            float g  = 1.0f - 2.0f / (e2 + 1.0f);                       \
            float hp = (float)(HT)[rl * PITCH + col];                   \
            __builtin_nontemporal_store((1.0f - z) * g + z * hp,        \
                out + (row0 + rl) * HID + col);                         \
        }                                                               \
} while (0)

// ---- fused GRU cell ---------------------------------------------------------
// 256 persistent blocks (1/CU): blockIdx = bgrp*2 + nh. Block owns cols
// [nh*128, nh*128+128) and 16 row-tiles of BM=32. Each wave holds its ENTIRE
// B slice (16 cols x 256 K x 5 gates = 160 VGPRs) loaded ONCE -> the K-loop
// has zero global loads. x/h double-buffered bf16 in LDS, next tile woven in.
template<bool PACKED>
__global__ void __launch_bounds__(512, 2) gru_fused(
    const float* __restrict__ x,  const float* __restrict__ h,
    const __bf16* __restrict__ wb,
    const float* __restrict__ w_ir, const float* __restrict__ w_iz,
    const float* __restrict__ w_in, const float* __restrict__ w_hz,
    const float* __restrict__ w_hn,
    const float* __restrict__ b_ir, const float* __restrict__ b_iz,
    const float* __restrict__ b_in, const float* __restrict__ b_hz,
    const float* __restrict__ b_hn,
    float* __restrict__ out)
{
    __shared__ __bf16 xt0[BM * PITCH], ht0[BM * PITCH];   // 4 x 16.5 KB = 66 KB
    __shared__ __bf16 xt1[BM * PITCH], ht1[BM * PITCH];

    const int t    = threadIdx.x;
    const int lane = t & 63;
    const int wn   = t >> 6;          // 0..7 : 16-col slice within the 128-col half
    const int lr   = lane & 15;
    const int lg   = lane >> 4;
    const int nh   = blockIdx.x & 1;  // N-half
    const int bgrp = blockIdx.x >> 1; // 0..127
    const int tb   = bgrp * 16;       // first of 16 row-tiles

    const int col = nh * 128 + wn * 16 + lr;   // this lane's output column

    // ---- resident B: load once (160 VGPRs) ----------------------------------
    bf16x8 Breg[8][5];
    if (PACKED) {
        const __bf16* wbase = wb + (nh * 8 + wn) * 512 + lane * 8;
#pragma unroll
        for (int ks = 0; ks < 8; ++ks)
#pragma unroll
            for (int g = 0; g < 5; ++g)
                Breg[ks][g] = *(const bf16x8*)(wbase + (ks * 5 + g) * 8192);
    } else {
        const float* wsrc[5] = { w_ir, w_iz, w_in, w_hz, w_hn };
        const int brow = nh * 128 + wn * 16 + (lane & 15);
#pragma unroll
        for (int ks = 0; ks < 8; ++ks)
#pragma unroll
            for (int g = 0; g < 5; ++g) {
                const float* pp = wsrc[g] + brow * HID + ks * 32 + lg * 8;
                CVT8(Breg[ks][g], pp);
            }
    }

    // ---- biases (fixed per lane) --------------------------------------------
    const float bz  = b_iz[col] + b_hz[col];
    const float br  = b_ir[col] + b_hz[col];
    const float bnx = b_in[col];
    const float bnh = b_hn[col];

    // ---- bulk-stage first tile into buf0 ------------------------------------
    {
        const size_t row0 = (size_t)tb * BM;
        f32x4 vx[4], vh[4];
#pragma unroll
        for (int i = 0; i < 4; ++i) {
            int e = i * 512 + t, r = e >> 6, c4 = (e & 63) * 4;
            vx[i] = __builtin_nontemporal_load((const f32x4*)(x + (row0 + r) * HID + c4));
            vh[i] = __builtin_nontemporal_load((const f32x4*)(h + (row0 + r) * HID + c4));
        }
#pragma unroll
        for (int i = 0; i < 4; ++i) {
            int e = i * 512 + t, r = e >> 6, c4 = (e & 63) * 4;
            bf16x4 bx, bh;
            bx[0]=(__bf16)vx[i][0]; bx[1]=(__bf16)vx[i][1]; bx[2]=(__bf16)vx[i][2]; bx[3]=(__bf16)vx[i][3];
            bh[0]=(__bf16)vh[i][0]; bh[1]=(__bf16)vh[i][1]; bh[2]=(__bf16)vh[i][2]; bh[3]=(__bf16)vh[i][3];
            *(bf16x4*)(xt0 + r * PITCH + c4) = bx;
            *(bf16x4*)(ht0 + r * PITCH + c4) = bh;
        }
    }
    __syncthreads();

    // ---- 16 tiles, compile-time buffer alternation --------------------------
    for (int it2 = 0; it2 < 8; ++it2) {
        TILE_BODY(xt0, ht0, xt1, ht1, tb + it2 * 2, true);
        __syncthreads();
        TILE_BODY(xt1, ht1, xt0, ht0, tb + it2 * 2 + 1, it2 < 7);
        __syncthreads();
    }
}

extern "C" void kernel_launch(void* const* d_in, const int* in_sizes, int n_in,
                              void* d_out, int out_size, void* d_ws, size_t ws_size,
                              hipStream_t stream) {
    const float* x    = (const float*)d_in[0];
    const float* h    = (const float*)d_in[1];
    const float* w_ir = (const float*)d_in[2];
    const float* b_ir = (const float*)d_in[3];
    const float* w_iz = (const float*)d_in[4];
    const float* b_iz = (const float*)d_in[5];
    const float* w_in = (const float*)d_in[6];
    const float* b_in = (const float*)d_in[7];
    const float* w_hz = (const float*)d_in[8];
    const float* b_hz = (const float*)d_in[9];
    const float* w_hn = (const float*)d_in[10];
    const float* b_hn = (const float*)d_in[11];
    float* out = (float*)d_out;

    const size_t wb_bytes = (size_t)5 * HID * HID * sizeof(__bf16);   // 640 KB

    if (ws_size >= wb_bytes) {
        __bf16* wb = (__bf16*)d_ws;
        prepack_frag<<<160, 256, 0, stream>>>(w_ir, w_iz, w_in, w_hz, w_hn, wb);
        gru_fused<true><<<256, 512, 0, stream>>>(
            x, h, wb, nullptr, nullptr, nullptr, nullptr, nullptr,
            b_ir, b_iz, b_in, b_hz, b_hn, out);
    } else {
        gru_fused<false><<<256, 512, 0, stream>>>(
            x, h, nullptr, w_ir, w_iz, w_in, w_hz, w_hn,
            b_ir, b_iz, b_in, b_hz, b_hn, out);
    }
}

// Round 13
// 124.055 us; speedup vs baseline: 2.9992x; 1.0612x over previous
//
#include <hip/hip_runtime.h>
#include <hip/hip_bf16.h>

typedef __bf16 bf16x8 __attribute__((ext_vector_type(8)));
typedef __bf16 bf16x4 __attribute__((ext_vector_type(4)));
typedef float  f32x4  __attribute__((ext_vector_type(4)));

#define HID   256
#define BM    64    // rows per block tile
#define PITCH 264   // bf16 elems per LDS row (16B-aligned; ~2-way banks, proven)
#define TPB   16    // tiles per persistent block

// gate order: 0=ir 1=iz 2=in 3=hz 4=hn
#define MFMA1(D, A_, B_) D = __builtin_amdgcn_mfma_f32_16x16x32_bf16(A_, B_, D, 0, 0, 0)

#define CVT8(DST, PP) do {                                              \
    float4 c0_ = *(const float4*)(PP), c1_ = *(const float4*)((PP) + 4);\
    DST[0]=(__bf16)c0_.x; DST[1]=(__bf16)c0_.y; DST[2]=(__bf16)c0_.z; DST[3]=(__bf16)c0_.w; \
    DST[4]=(__bf16)c1_.x; DST[5]=(__bf16)c1_.y; DST[6]=(__bf16)c1_.z; DST[7]=(__bf16)c1_.w; \
} while (0)

// one K-step: 8 ds_read_b128 + 24 MFMA, B from resident registers (no loads)
#define KSTEP(XT, HT, KS) do {                                          \
    const int kb = (KS) * 32 + lg * 8;                                  \
    bf16x8 ax[4], ah[4];                                                \
    _Pragma("unroll")                                                   \
    for (int mf = 0; mf < 4; ++mf) {                                    \
        ax[mf] = *(const bf16x8*)((XT) + (mf * 16 + lr) * PITCH + kb);  \
        ah[mf] = *(const bf16x8*)((HT) + (mf * 16 + lr) * PITCH + kb);  \
    }                                                                   \
    _Pragma("unroll")                                                   \
    for (int mf = 0; mf < 4; ++mf) {                                    \
        MFMA1(az[mf],  ax[mf], Breg[KS][1]);                            \
        MFMA1(ar[mf],  ax[mf], Breg[KS][0]);                            \
        MFMA1(anx[mf], ax[mf], Breg[KS][2]);                            \
    }                                                                   \
    _Pragma("unroll")                                                   \
    for (int mf = 0; mf < 4; ++mf) {                                    \
        MFMA1(az[mf],  ah[mf], Breg[KS][3]);                            \
        MFMA1(ar[mf],  ah[mf], Breg[KS][3]);                            \
        MFMA1(anh[mf], ah[mf], Breg[KS][4]);                            \
    }                                                                   \
} while (0)

// staging group G (rows G*16..G*16+15 of next tile): 4 chunks/thread/tensor
#define PFI(G) do {                                                     \
    _Pragma("unroll")                                                   \
    for (int j = 0; j < 4; ++j) {                                       \
        int id = (G) * 1024 + j * 256 + t;                              \
        int r_ = id >> 6, c4_ = (id & 63) * 4;                          \
        px[j] = *(const f32x4*)(x + (prow0 + r_) * HID + c4_);          \
        ph[j] = *(const f32x4*)(h + (prow0 + r_) * HID + c4_);          \
    }                                                                   \
} while (0)

#define PFS(XW, HW, G) do {                                             \
    _Pragma("unroll")                                                   \
    for (int j = 0; j < 4; ++j) {                                       \
        int id = (G) * 1024 + j * 256 + t;                              \
        int r_ = id >> 6, c4_ = (id & 63) * 4;                          \
        bf16x4 bx_, bh_;                                                \
        bx_[0]=(__bf16)px[j][0]; bx_[1]=(__bf16)px[j][1]; bx_[2]=(__bf16)px[j][2]; bx_[3]=(__bf16)px[j][3]; \
        bh_[0]=(__bf16)ph[j][0]; bh_[1]=(__bf16)ph[j][1]; bh_[2]=(__bf16)ph[j][2]; bh_[3]=(__bf16)ph[j][3]; \
        *(bf16x4*)((XW) + r_ * PITCH + c4_) = bx_;                      \
        *(bf16x4*)((HW) + r_ * PITCH + c4_) = bh_;                      \
    }                                                                   \
} while (0)

// full tile: 8 K-steps (zero global loads), staging woven in, fused epilogue
#define TILE_BODY(XT, HT, XW, HW, TILE, PF) do {                        \
    const bool pf_ = (PF);                                              \
    const size_t prow0 = (size_t)((TILE) + 1) * BM;                     \
    f32x4 px[4], ph[4];                                                 \
    f32x4 az[4], ar[4], anx[4], anh[4];                                 \
    _Pragma("unroll")                                                   \
    for (int mf = 0; mf < 4; ++mf) {                                    \
        az[mf] = (f32x4)0.0f; ar[mf] = (f32x4)0.0f;                     \
        anx[mf] = (f32x4)0.0f; anh[mf] = (f32x4)0.0f;                   \
    }                                                                   \
    if (pf_) PFI(0);                                                    \
    KSTEP(XT, HT, 0); KSTEP(XT, HT, 1);                                 \
    if (pf_) { PFS(XW, HW, 0); PFI(1); }                                \
    KSTEP(XT, HT, 2); KSTEP(XT, HT, 3);                                 \
    if (pf_) { PFS(XW, HW, 1); PFI(2); }                                \
    KSTEP(XT, HT, 4); KSTEP(XT, HT, 5);                                 \
    if (pf_) { PFS(XW, HW, 2); PFI(3); }                                \
    KSTEP(XT, HT, 6); KSTEP(XT, HT, 7);                                 \
    if (pf_) PFS(XW, HW, 3);                                            \
    const size_t row0 = (size_t)(TILE) * BM;                            \
    _Pragma("unroll")                                                   \
    for (int mf = 0; mf < 4; ++mf)                                      \
        _Pragma("unroll")                                               \
        for (int i = 0; i < 4; ++i) {                                   \
            int rl = mf * 16 + lg * 4 + i;                              \
            float z  = 1.0f / (1.0f + __expf(-(az[mf][i] + bz)));       \
            float r  = 1.0f / (1.0f + __expf(-(ar[mf][i] + br)));       \
            float e2 = __expf(2.0f * (anx[mf][i] + bnx + r * (anh[mf][i] + bnh))); \
            float g  = 1.0f - 2.0f / (e2 + 1.0f);                       \
            float hp = (float)(HT)[rl * PITCH + col];                   \
            __builtin_nontemporal_store((1.0f - z) * g + z * hp,        \
                out + (row0 + rl) * HID + col);                         \
        }                                                               \
} while (0)

// ---- fused GRU cell ---------------------------------------------------------
// 256 persistent blocks of 256 threads (4 waves), __launch_bounds__(256,1):
// up to 512 unified regs/wave -> the resident-B set can NOT spill.
// Block b: col-group cg=b&3 (cols cg*64..cg*64+63), row-tiles (b>>2)*16+it.
// Wave wn owns 64 rows x 16 cols; holds its whole B (8 K-steps x 5 gates =
// 160 VGPRs) loaded ONCE; K-loop = ds_read + MFMA only. LDS x/h dbuf 132 KB.
__global__ void __launch_bounds__(256, 1) gru_fused(
    const float* __restrict__ x,  const float* __restrict__ h,
    const float* __restrict__ w_ir, const float* __restrict__ w_iz,
    const float* __restrict__ w_in, const float* __restrict__ w_hz,
    const float* __restrict__ w_hn,
    const float* __restrict__ b_ir, const float* __restrict__ b_iz,
    const float* __restrict__ b_in, const float* __restrict__ b_hz,
    const float* __restrict__ b_hn,
    float* __restrict__ out)
{
    __shared__ __bf16 xt0[BM * PITCH], ht0[BM * PITCH];   // 2 x 33 KB
    __shared__ __bf16 xt1[BM * PITCH], ht1[BM * PITCH];   // 2 x 33 KB

    const int t    = threadIdx.x;
    const int lane = t & 63;
    const int wn   = t >> 6;          // 0..3 : 16-col slice within col-group
    const int lr   = lane & 15;
    const int lg   = lane >> 4;
    const int cg   = blockIdx.x & 3;  // col-group (64 cols)
    const int tb   = (blockIdx.x >> 2) * TPB;

    const int col = cg * 64 + wn * 16 + lr;   // this lane's output column

    // ---- resident B: load once from fp32 weights (160 VGPRs) ---------------
    const float* wsrc[5] = { w_ir, w_iz, w_in, w_hz, w_hn };
    bf16x8 Breg[8][5];
#pragma unroll
    for (int ks = 0; ks < 8; ++ks)
#pragma unroll
        for (int g = 0; g < 5; ++g) {
            const float* pp = wsrc[g] + (size_t)col * HID + ks * 32 + lg * 8;
            CVT8(Breg[ks][g], pp);
        }

    // ---- biases (fixed per lane) --------------------------------------------
    const float bz  = b_iz[col] + b_hz[col];
    const float br  = b_ir[col] + b_hz[col];
    const float bnx = b_in[col];
    const float bnh = b_hn[col];

    // ---- bulk-stage first tile into buf0 ------------------------------------
    {
        const size_t row0 = (size_t)tb * BM;
#pragma unroll
        for (int g = 0; g < 4; ++g) {
            f32x4 vx[4], vh[4];
#pragma unroll
            for (int j = 0; j < 4; ++j) {
                int id = g * 1024 + j * 256 + t;
                int r = id >> 6, c4 = (id & 63) * 4;
                vx[j] = *(const f32x4*)(x + (row0 + r) * HID + c4);
                vh[j] = *(const f32x4*)(h + (row0 + r) * HID + c4);
            }
#pragma unroll
            for (int j = 0; j < 4; ++j) {
                int id = g * 1024 + j * 256 + t;
                int r = id >> 6, c4 = (id & 63) * 4;
                bf16x4 bx, bh;
                bx[0]=(__bf16)vx[j][0]; bx[1]=(__bf16)vx[j][1]; bx[2]=(__bf16)vx[j][2]; bx[3]=(__bf16)vx[j][3];
                bh[0]=(__bf16)vh[j][0]; bh[1]=(__bf16)vh[j][1]; bh[2]=(__bf16)vh[j][2]; bh[3]=(__bf16)vh[j][3];
                *(bf16x4*)(xt0 + r * PITCH + c4) = bx;
                *(bf16x4*)(ht0 + r * PITCH + c4) = bh;
            }
        }
    }
    __syncthreads();

    // ---- 16 tiles, compile-time buffer alternation --------------------------
    for (int it2 = 0; it2 < TPB / 2; ++it2) {
        TILE_BODY(xt0, ht0, xt1, ht1, tb + it2 * 2, true);
        __syncthreads();
        TILE_BODY(xt1, ht1, xt0, ht0, tb + it2 * 2 + 1, it2 < TPB / 2 - 1);
        __syncthreads();
    }
}

extern "C" void kernel_launch(void* const* d_in, const int* in_sizes, int n_in,
                              void* d_out, int out_size, void* d_ws, size_t ws_size,
                              hipStream_t stream) {
    const float* x    = (const float*)d_in[0];
    const float* h    = (const float*)d_in[1];
    const float* w_ir = (const float*)d_in[2];
    const float* b_ir = (const float*)d_in[3];
    const float* w_iz = (const float*)d_in[4];
    const float* b_iz = (const float*)d_in[5];
    const float* w_in = (const float*)d_in[6];
    const float* b_in = (const float*)d_in[7];
    const float* w_hz = (const float*)d_in[8];
    const float* b_hz = (const float*)d_in[9];
    const float* w_hn = (const float*)d_in[10];
    const float* b_hn = (const float*)d_in[11];
    float* out = (float*)d_out;

    // grid: (65536/64 row-tiles / 16 per block) * 4 col-groups = 256 blocks
    gru_fused<<<256, 256, 0, stream>>>(
        x, h, w_ir, w_iz, w_in, w_hz, w_hn,
        b_ir, b_iz, b_in, b_hz, b_hn, out);
}